// Round 10
// baseline (438.535 us; speedup 1.0000x reference)
//
#include <hip/hip_runtime.h>

// Problem constants: T=1024, B=256, H=20
#define T_N 1024
#define B_N 256
#define H_N 20
#define NW  8            // waves per block
#define NDW (NW - 1)     // dot waves
#define SIH 1096         // I-history row stride in HALVES (conflict-free layout, see R5)

typedef _Float16 h8_t __attribute__((ext_vector_type(8)));

#if __has_builtin(__builtin_amdgcn_fdot2)
#define DOT8(acc, mv, iv)                                                           \
    acc = __builtin_amdgcn_fdot2(__builtin_shufflevector(mv, mv, 0, 1),             \
                                 __builtin_shufflevector(iv, iv, 0, 1), acc, false);\
    acc = __builtin_amdgcn_fdot2(__builtin_shufflevector(mv, mv, 2, 3),             \
                                 __builtin_shufflevector(iv, iv, 2, 3), acc, false);\
    acc = __builtin_amdgcn_fdot2(__builtin_shufflevector(mv, mv, 4, 5),             \
                                 __builtin_shufflevector(iv, iv, 4, 5), acc, false);\
    acc = __builtin_amdgcn_fdot2(__builtin_shufflevector(mv, mv, 6, 7),             \
                                 __builtin_shufflevector(iv, iv, 6, 7), acc, false);
#else
#define DOT8(acc, mv, iv)                                                           \
    _Pragma("unroll")                                                               \
    for (int _k = 0; _k < 8; ++_k) acc = fmaf((float)mv[_k], (float)iv[_k], acc);
#endif

__device__ __forceinline__ float rdlane_i(float v, int lane) {
    return __uint_as_float((unsigned)__builtin_amdgcn_readlane((int)__float_as_uint(v), lane));
}
__device__ __forceinline__ float fast_tanh(float x) {
    const float e = __expf(2.0f * x);
    return fmaf(-2.0f, __builtin_amdgcn_rcpf(e + 1.0f), 1.0f);
}
__device__ __forceinline__ float fast_sigmoid(float x) {
    return __builtin_amdgcn_rcpf(1.0f + __expf(-x));
}

// explicit literal-token repetition (tokens must be plain literals for ##)
#define REP64(F) \
    F(0) F(1) F(2) F(3) F(4) F(5) F(6) F(7) F(8) F(9) F(10) F(11) F(12) F(13) \
    F(14) F(15) F(16) F(17) F(18) F(19) F(20) F(21) F(22) F(23) F(24) F(25)   \
    F(26) F(27) F(28) F(29) F(30) F(31) F(32) F(33) F(34) F(35) F(36) F(37)   \
    F(38) F(39) F(40) F(41) F(42) F(43) F(44) F(45) F(46) F(47) F(48) F(49)   \
    F(50) F(51) F(52) F(53) F(54) F(55) F(56) F(57) F(58) F(59) F(60) F(61)   \
    F(62) F(63)

// ---------------------------------------------------------------------------
// R10: DIAGNOSTIC ROUND. Six surgical nulls on the step body (R1,R2,R4,R5,
// R7,R9) vs a static model predicting ~25-30cy/step while ~90cy is observed.
// Stop guessing: co-launch ablation variants, read their durations from the
// rocprof dispatch table.
//   MODE 1: exact R6 kernel semantics, 4 idempotent reps, real me, real
//           stores -> correct output AND the 4x-scan anchor.
//   MODE 2: steps removed (dots/merge/epilogue-LDS/barriers kept) -> floor.
//   MODE 3: dot waves dormant (full steps, sink stores) -> contention probe.
//   MODE 4: full steps+dots, global stores->sink        -> store-cost probe.
// Modes 2-4 stage t[] as fake me (never read me bufs; their sink writes to
// d_ws[0..3KB) corrupt me_f AFTER mode 1 consumed it). Liveness for sink
// modes flows dots->P->ps->sink and steps->oS/oI->sink (no DCE, rule #17).
// Pre-committed reads: steps=(M4-M2)/4, stores=(M1-M4)/4, dots=(M4-M3)/4,
// floor=M2/4.
// ---------------------------------------------------------------------------
__global__ __launch_bounds__(512, 1) void me_kernel(
    const float* __restrict__ t,
    const float* __restrict__ w1, const float* __restrict__ b1,
    const float* __restrict__ w2, const float* __restrict__ b2,
    const float* __restrict__ w3, const float* __restrict__ b3,
    const float* __restrict__ w4, const float* __restrict__ b4,
    float* __restrict__ me_f,        // [1024] fp32
    _Float16* __restrict__ me_h)     // [1024] fp16
{
    const int gid = blockIdx.x * 512 + threadIdx.x;   // 2 blocks x 512 = 1024
    const float x = t[gid];

    float h1[H_N], h2[H_N];
#pragma unroll
    for (int k = 0; k < H_N; ++k) h1[k] = fast_tanh(fmaf(x, w1[k], b1[k]));

#pragma unroll 4
    for (int k = 0; k < H_N; ++k) {
        float a = b2[k];
#pragma unroll
        for (int j = 0; j < H_N; ++j) a = fmaf(h1[j], w2[j * H_N + k], a);
        h2[k] = fast_tanh(a);
    }

    float a4 = b4[0];
#pragma unroll 4
    for (int k = 0; k < H_N; ++k) {
        float a = b3[k];
#pragma unroll
        for (int j = 0; j < H_N; ++j) a = fmaf(h2[j], w3[j * H_N + k], a);
        a4 = fmaf(fast_tanh(a), w4[k], a4);
    }

    const float meval = fast_sigmoid(a4);
    me_f[gid] = meval;
    me_h[gid] = (_Float16)meval;
}

template <int MODE>
__global__ __launch_bounds__(512, 1) void scan_kernel(
    const float* __restrict__ me_f,
    const _Float16* __restrict__ me_h,
    const float* __restrict__ t,
    const float* __restrict__ y,
    const float* __restrict__ beta_p,
    const float* __restrict__ gamma_p,
    float* __restrict__ out,     // [solution (T*B*3) | diff (T*B*3)]
    float* __restrict__ sink)    // d_ws (modes 2-4 write 1 float/block)
{
    __shared__ __align__(16) float    sMeF[T_N];      // fp32 me
    __shared__ __align__(16) _Float16 sMeH[T_N];      // fp16 me (dot operand A)
    __shared__ __align__(16) _Float16 sIhR[8 * SIH];  // 8 shifted fp16 I-history rows
    __shared__ __align__(16) float    PA[2][64][4];   // dot partials, waves 1-4
    __shared__ __align__(16) float    PB[2][64][4];   // dot partials, waves 5-7 (+zero slot)

    const int b   = blockIdx.x;
    const int tid = threadIdx.x;
    const int wid = tid >> 6;
    const int L   = tid & 63;

    // per-lane dot-geometry constants (chunk-invariant)
    const int f    = (-L) & 7;            // misalignment of lane L's me window
    const int R8   = L + f;               // L rounded up to multiple of 8
    const int row  = L & 7;               // I-history row for this lane
    const int iofs = row * SIH + (f ? 0 : 8);

    // zero the row front-pads (slots representing I[<0])
    if (tid < 64) sIhR[(tid >> 3) * SIH + (tid & 7)] = (_Float16)0.0f;
    // zero PA/PB entirely (512 floats each; mode 3 reads them unwritten)
    ((float*)PA)[tid] = 0.0f;
    ((float*)PB)[tid] = 0.0f;

    // ---- stage me (mode 1: real; modes 2-4: t-values, never touch me bufs) ----
#pragma unroll
    for (int v = 0; v < 2; ++v) {
        const int mi = tid + v * 512;
        if (MODE == 1) {
            sMeF[mi] = me_f[mi];
            sMeH[mi] = me_h[mi];
        } else {
            const float tv = t[mi];
            sMeF[mi] = tv;
            sMeH[mi] = (_Float16)tv;
        }
    }

    // ---- scalars / state ----
    const float dt    = t[0] - t[1];
    const float beta  = beta_p[0];
    const float gma   = gamma_p[0];
    const float invdt = 1.0f / dt;
    const float dt2   = dt * dt;

    const float S0 = y[b * 3 + 0];
    const float I0 = y[b * 3 + 1];
    const float R0 = y[b * 3 + 2];
    const float TOT = S0 + I0 + R0;     // SIR total conserved

    // publish I[0] into all 8 rows
    if (tid < 8) sIhR[tid * SIH + 8 - tid] = (_Float16)I0;

    float* __restrict__ diff = out + (size_t)T_N * B_N * 3;
    if (MODE == 1 && tid < 3) diff[((size_t)(T_N - 1) * B_N + b) * 3 + tid] = 0.0f;

    __syncthreads();   // sMeF/sMeH/pads/I0/PA/PB visible

    // fixup me weights (chunk-invariant, UNSCALED — applied to raw P sums)
    float mf[7];
#pragma unroll
    for (int d = 1; d <= 7; ++d) mf[d - 1] = sMeF[T_N - 64 - L - d];

    const float dtb   = dt * beta;
    const float ndtb  = -dtb;
    const float c1    = fmaf(-dt, gma, 1.0f);     // 1 - dt*gamma
    const float meT1s = dt2 * sMeF[T_N - 1];      // dt^2 * me[T-1]

    float sink_acc = 0.0f;

    // register me-tables (dt^2-scaled): 128 NAMED scalars
#define TBLDECL(k) float rm_##k, rn_##k;
    REP64(TBLDECL)
#undef TBLDECL
    if (wid == 0) {
#define TBLINIT(k)                                                          \
        rm_##k = (((k) < L) ? sMeF[T_N - L + (k)] : 0.0f) * dt2;            \
        rn_##k = dt2 * sMeF[T_N - 64 - L + (k)];
        REP64(TBLINIT)
#undef TBLINIT
#define TBLPIN(k) asm volatile("" : "+v"(rm_##k), "+v"(rn_##k));
        REP64(TBLPIN)
#undef TBLPIN
        // wave0 priority: serial VALU wave vs 7 LDS-heavy dot waves (T5)
        __builtin_amdgcn_s_setprio(3);
    }

    // serial step M_ (R6 form: cndmask capture, distance-1 readlane)
#define STEPB(M_, FIRST_)                                               \
    {                                                                   \
        const float sum = (FIRST_) ? pre : fmaf(meT1s, I, pre);         \
        float pnx = pre;                                                \
        if ((M_) < 63) pnx = rdlane_i(acc_cur, (M_) + 1);               \
        const float a  = fmaf(dtb, S, c1);                              \
        const float bb = fmaf(ndtb, I, 1.0f);                           \
        S = fmaf(bb, S, sum);                                           \
        I = I * a;                                                      \
        const bool cap = (L == (M_));                                   \
        oS = cap ? S : oS;                                              \
        oI = cap ? I : oI;                                              \
        acc_cur = fmaf(rm_##M_, I, acc_cur);                            \
        acc_nxt = fmaf(rn_##M_, I, acc_nxt);                            \
        pre = pnx;                                                      \
    }
#define STEP_GE1(M_) if ((M_) >= 1) STEPB(M_, false)
#define STEP_GE2(M_) if ((M_) >= 2) STEPB(M_, false)

#pragma unroll 1
    for (int rep = 0; rep < 4; ++rep) {
        float S = S0, I = I0, oS = S0, oI = I0;
        float acc_cur = 0.0f, acc_nxt = 0.0f, pre = 0.0f;
        float carryS = S0, carryI = I0;

#pragma unroll 1
        for (int c = 0; c < 16; ++c) {
            if (wid == 0) {
                if (c == 0) {
                    if (MODE != 2) {
                        acc_cur = rm_0 * I;
                        acc_nxt = rn_0 * I;
                        pre = rdlane_i(acc_cur, 1);
                        STEPB(1, true)
                        REP64(STEP_GE2)
                    }
                } else {
                    const float4 pa = *(const float4*)&PA[c & 1][L][0];
                    const float4 pb = *(const float4*)&PB[c & 1][L][0];
                    const float ps = ((pa.x + pa.y) + (pa.z + pa.w)) +
                                     ((pb.x + pb.y) + (pb.z + pb.w));
                    if (MODE != 2) {
                        acc_cur = fmaf(dt2, ps, acc_nxt);
                        acc_nxt = 0.0f;
                        pre = rdlane_i(acc_cur, 0);
                        STEPB(0, true)
                        REP64(STEP_GE1)
                    } else {
                        sink_acc += ps;   // keep dots+merge live
                    }
                }

                // ---- chunk epilogue (wave 0) ----
                const int j = 64 * c + L;
                const _Float16 hI = (_Float16)oI;
#pragma unroll
                for (int r = 0; r < 8; ++r) sIhR[r * SIH + 8 + (j - r)] = hI;

                float sm1 = __shfl_up(oS, 1);
                float im1 = __shfl_up(oI, 1);
                if (L == 0) { sm1 = carryS; im1 = carryI; }

                if (MODE == 1) {
                    const float oR = TOT - oS - oI;
                    const size_t so = ((size_t)j * B_N + b) * 3;
                    out[so + 0] = oS;
                    out[so + 1] = oI;
                    out[so + 2] = oR;
                    if (j > 0) {
                        const float d0 = (oS - sm1) * invdt;
                        const float d1 = (oI - im1) * invdt;
                        const float d2 = -d0 - d1;
                        const size_t dofs = ((size_t)(j - 1) * B_N + b) * 3;
                        diff[dofs + 0] = d0;
                        diff[dofs + 1] = d1;
                        diff[dofs + 2] = d2;
                    }
                } else {
                    sink_acc += oS + oI + sm1 + im1;   // keep everything live
                }
                carryS = rdlane_i(oS, 63);
                carryI = rdlane_i(oI, 63);
            } else if (c < 15) {
                if (MODE != 3) {
                    // history dot for chunk c+1 over tau < 64c
                    const int w    = wid - 1;
                    const int G    = 8 * c;
                    const int idx0 = (T_N - 64 * (c + 1)) - R8;
                    float p0 = 0.0f, p1 = 0.0f;
                    int s = w;
                    for (; s + NDW < G; s += 2 * NDW) {
                        const h8_t mv0 = *(const h8_t*)&sMeH[idx0 + 8 * s];
                        const h8_t iv0 = *(const h8_t*)&sIhR[iofs + 8 * s];
                        const h8_t mv1 = *(const h8_t*)&sMeH[idx0 + 8 * (s + NDW)];
                        const h8_t iv1 = *(const h8_t*)&sIhR[iofs + 8 * (s + NDW)];
                        DOT8(p0, mv0, iv0)
                        DOT8(p1, mv1, iv1)
                    }
                    if (s < G) {
                        const h8_t mv0 = *(const h8_t*)&sMeH[idx0 + 8 * s];
                        const h8_t iv0 = *(const h8_t*)&sIhR[iofs + 8 * s];
                        DOT8(p0, mv0, iv0)
                    }
                    float p = p0 + p1;
                    if (w == 0) {
#pragma unroll
                        for (int d = 1; d <= 7; ++d) {
                            const float ih = (float)sIhR[8 + 64 * c - d];   // row 0
                            if (d <= f) p = fmaf(mf[d - 1], ih, p);
                        }
                    }
                    if (w < 4) PA[(c + 1) & 1][L][w] = p;
                    else       PB[(c + 1) & 1][L][w - 4] = p;
                }
            }
            __syncthreads();
        }
    }
#undef STEPB
#undef STEP_GE1
#undef STEP_GE2

    if (MODE != 1) {
        if (tid == 0) sink[(MODE - 2) * B_N + b] = sink_acc;
    }
}

// ---------------------------------------------------------------------------
// Launcher: me_kernel, then mode 1 (real output, 4 reps, reads real me),
// then ablation modes 2/3/4 (t-as-me, sink to d_ws[0..3KB)).
// ---------------------------------------------------------------------------
extern "C" void kernel_launch(void* const* d_in, const int* in_sizes, int n_in,
                              void* d_out, int out_size, void* d_ws, size_t ws_size,
                              hipStream_t stream) {
    const float* t     = (const float*)d_in[0];
    const float* y     = (const float*)d_in[1];
    const float* w1    = (const float*)d_in[2];
    const float* b1    = (const float*)d_in[3];
    const float* w2    = (const float*)d_in[4];
    const float* b2    = (const float*)d_in[5];
    const float* w3    = (const float*)d_in[6];
    const float* b3    = (const float*)d_in[7];
    const float* w4    = (const float*)d_in[8];
    const float* b4    = (const float*)d_in[9];
    const float* beta  = (const float*)d_in[10];
    const float* gamma = (const float*)d_in[11];

    float*    me_f = (float*)d_ws;
    _Float16* me_h = (_Float16*)((char*)d_ws + 4096);
    float*    sink = (float*)d_ws;
    float*    outp = (float*)d_out;

    me_kernel<<<2, 512, 0, stream>>>(t, w1, b1, w2, b2, w3, b3, w4, b4, me_f, me_h);
    scan_kernel<1><<<B_N, 512, 0, stream>>>(me_f, me_h, t, y, beta, gamma, outp, sink);
    scan_kernel<2><<<B_N, 512, 0, stream>>>(me_f, me_h, t, y, beta, gamma, outp, sink);
    scan_kernel<3><<<B_N, 512, 0, stream>>>(me_f, me_h, t, y, beta, gamma, outp, sink);
    scan_kernel<4><<<B_N, 512, 0, stream>>>(me_f, me_h, t, y, beta, gamma, outp, sink);
}

// Round 11
// 114.713 us; speedup vs baseline: 3.8229x; 3.8229x over previous
//
#include <hip/hip_runtime.h>

// Problem constants: T=1024, B=256, H=20
#define T_N 1024
#define B_N 256
#define H_N 20
#define NW  4            // waves per block (R11: wave0 gets SIMD0 alone)
#define NDW (NW - 1)     // dot waves
#define SIH 1096         // I-history row stride in HALVES (conflict-free layout, see R5)

typedef _Float16 h8_t __attribute__((ext_vector_type(8)));

#if __has_builtin(__builtin_amdgcn_fdot2)
#define DOT8(acc, mv, iv)                                                           \
    acc = __builtin_amdgcn_fdot2(__builtin_shufflevector(mv, mv, 0, 1),             \
                                 __builtin_shufflevector(iv, iv, 0, 1), acc, false);\
    acc = __builtin_amdgcn_fdot2(__builtin_shufflevector(mv, mv, 2, 3),             \
                                 __builtin_shufflevector(iv, iv, 2, 3), acc, false);\
    acc = __builtin_amdgcn_fdot2(__builtin_shufflevector(mv, mv, 4, 5),             \
                                 __builtin_shufflevector(iv, iv, 4, 5), acc, false);\
    acc = __builtin_amdgcn_fdot2(__builtin_shufflevector(mv, mv, 6, 7),             \
                                 __builtin_shufflevector(iv, iv, 6, 7), acc, false);
#else
#define DOT8(acc, mv, iv)                                                           \
    _Pragma("unroll")                                                               \
    for (int _k = 0; _k < 8; ++_k) acc = fmaf((float)mv[_k], (float)iv[_k], acc);
#endif

__device__ __forceinline__ float rdlane_i(float v, int lane) {
    return __uint_as_float((unsigned)__builtin_amdgcn_readlane((int)__float_as_uint(v), lane));
}
__device__ __forceinline__ float fast_tanh(float x) {
    const float e = __expf(2.0f * x);
    return fmaf(-2.0f, __builtin_amdgcn_rcpf(e + 1.0f), 1.0f);
}
__device__ __forceinline__ float fast_sigmoid(float x) {
    return __builtin_amdgcn_rcpf(1.0f + __expf(-x));
}

// explicit literal-token repetition (tokens must be plain literals for ##)
#define REP64(F) \
    F(0) F(1) F(2) F(3) F(4) F(5) F(6) F(7) F(8) F(9) F(10) F(11) F(12) F(13) \
    F(14) F(15) F(16) F(17) F(18) F(19) F(20) F(21) F(22) F(23) F(24) F(25)   \
    F(26) F(27) F(28) F(29) F(30) F(31) F(32) F(33) F(34) F(35) F(36) F(37)   \
    F(38) F(39) F(40) F(41) F(42) F(43) F(44) F(45) F(46) F(47) F(48) F(49)   \
    F(50) F(51) F(52) F(53) F(54) F(55) F(56) F(57) F(58) F(59) F(60) F(61)   \
    F(62) F(63)

// ---------------------------------------------------------------------------
// R11: 4-WAVE BLOCK — wave0 alone on its SIMD. Evidence: R10's rep-scaling
// (M1 4-rep=115us -> steady ~25us/rep vs static issue+dep model ~13us) shows
// a ~2x op-count-PROPORTIONAL inflation on the serial chain; that is the
// signature of SIMD issue arbitration with the co-resident dot wave (8 waves
// / 4 SIMDs), which setprio only dented (+1.5us, R5). With 256 threads the
// round-robin wave->SIMD mapping gives wave0 a private SIMD: zero issue
// competition. Dot capacity check: worst chunk c=14 = 112 segments/3 waves
// ~= 1.1k cy < wave0's ~2k cy chunk -> dots stay hidden under the chain.
// P merge simplifies to ONE ds_read_b128 (3 partials + zeroed slot 3).
// Base otherwise identical to R6 (best: 114.2us): me_kernel split,
// setprio(3), distance-1 readlane, cndmask capture, dt^2-folded algebra.
// ---------------------------------------------------------------------------
__global__ __launch_bounds__(512, 1) void me_kernel(
    const float* __restrict__ t,
    const float* __restrict__ w1, const float* __restrict__ b1,
    const float* __restrict__ w2, const float* __restrict__ b2,
    const float* __restrict__ w3, const float* __restrict__ b3,
    const float* __restrict__ w4, const float* __restrict__ b4,
    float* __restrict__ me_f,        // [1024] fp32
    _Float16* __restrict__ me_h)     // [1024] fp16
{
    const int gid = blockIdx.x * 512 + threadIdx.x;   // 2 blocks x 512 = 1024
    const float x = t[gid];

    float h1[H_N], h2[H_N];
#pragma unroll
    for (int k = 0; k < H_N; ++k) h1[k] = fast_tanh(fmaf(x, w1[k], b1[k]));

#pragma unroll 4
    for (int k = 0; k < H_N; ++k) {
        float a = b2[k];
#pragma unroll
        for (int j = 0; j < H_N; ++j) a = fmaf(h1[j], w2[j * H_N + k], a);
        h2[k] = fast_tanh(a);
    }

    float a4 = b4[0];
#pragma unroll 4
    for (int k = 0; k < H_N; ++k) {
        float a = b3[k];
#pragma unroll
        for (int j = 0; j < H_N; ++j) a = fmaf(h2[j], w3[j * H_N + k], a);
        a4 = fmaf(fast_tanh(a), w4[k], a4);
    }

    const float meval = fast_sigmoid(a4);
    me_f[gid] = meval;
    me_h[gid] = (_Float16)meval;
}

__global__ __launch_bounds__(256, 1) void scan_kernel(
    const float* __restrict__ me_f,
    const _Float16* __restrict__ me_h,
    const float* __restrict__ t,
    const float* __restrict__ y,
    const float* __restrict__ beta_p,
    const float* __restrict__ gamma_p,
    float* __restrict__ out)     // [solution (T*B*3) | diff (T*B*3)]
{
    __shared__ __align__(16) float    sMeF[T_N];      // fp32 me
    __shared__ __align__(16) _Float16 sMeH[T_N];      // fp16 me (dot operand A)
    __shared__ __align__(16) _Float16 sIhR[8 * SIH];  // 8 shifted fp16 I-history rows
    __shared__ __align__(16) float    P[2][64][4];    // dot partials (slot 3 = 0)

    const int b   = blockIdx.x;
    const int tid = threadIdx.x;
    const int wid = tid >> 6;     // 0..3
    const int L   = tid & 63;

    // per-lane dot-geometry constants (chunk-invariant)
    const int f    = (-L) & 7;            // misalignment of lane L's me window
    const int R8   = L + f;               // L rounded up to multiple of 8
    const int row  = L & 7;               // I-history row for this lane
    const int iofs = row * SIH + (f ? 0 : 8);

    // zero the row front-pads (slots representing I[<0])
    if (tid < 64) sIhR[(tid >> 3) * SIH + (tid & 7)] = (_Float16)0.0f;
    // zero the unused P slot 3 for both parities
    if (tid < 128) P[tid >> 6][tid & 63][3] = 0.0f;

    // ---- stage me from global (computed by me_kernel): 4 values/thread ----
#pragma unroll
    for (int v = 0; v < 4; ++v) {
        const int mi = tid + v * 256;
        sMeF[mi] = me_f[mi];
        sMeH[mi] = me_h[mi];
    }

    // ---- scalars / state ----
    const float dt    = t[0] - t[1];
    const float beta  = beta_p[0];
    const float gma   = gamma_p[0];
    const float invdt = 1.0f / dt;
    const float dt2   = dt * dt;

    const float S0 = y[b * 3 + 0];
    const float I0 = y[b * 3 + 1];
    const float R0 = y[b * 3 + 2];
    const float TOT = S0 + I0 + R0;     // SIR total conserved

    // publish I[0] into all 8 rows
    if (tid < 8) sIhR[tid * SIH + 8 - tid] = (_Float16)I0;

    float* __restrict__ diff = out + (size_t)T_N * B_N * 3;
    if (tid < 3) diff[((size_t)(T_N - 1) * B_N + b) * 3 + tid] = 0.0f;

    __syncthreads();   // sMeF/sMeH/pads/I0/P-slot3 visible

    // fixup me weights (chunk-invariant, UNSCALED — applied to raw P sums)
    float mf[7];
#pragma unroll
    for (int d = 1; d <= 7; ++d) mf[d - 1] = sMeF[T_N - 64 - L - d];

    const float dtb   = dt * beta;
    const float ndtb  = -dtb;
    const float c1    = fmaf(-dt, gma, 1.0f);     // 1 - dt*gamma
    const float meT1s = dt2 * sMeF[T_N - 1];      // dt^2 * me[T-1]

    float S = S0, I = I0, oS = S0, oI = I0;
    float acc_cur = 0.0f, acc_nxt = 0.0f, pre = 0.0f;
    float carryS = S0, carryI = I0;

    // register me-tables (dt^2-scaled): 128 NAMED scalars
#define TBLDECL(k) float rm_##k, rn_##k;
    REP64(TBLDECL)
#undef TBLDECL
    if (wid == 0) {
#define TBLINIT(k)                                                          \
        rm_##k = (((k) < L) ? sMeF[T_N - L + (k)] : 0.0f) * dt2;            \
        rn_##k = dt2 * sMeF[T_N - 64 - L + (k)];
        REP64(TBLINIT)
#undef TBLINIT
#define TBLPIN(k) asm volatile("" : "+v"(rm_##k), "+v"(rn_##k));
        REP64(TBLPIN)
#undef TBLPIN
        // harmless now (wave0 alone on SIMD0); kept for consistency
        __builtin_amdgcn_s_setprio(3);
    }

    // serial step M_: entering (S,I) = y_{64c+M_-1}; produces y_{64c+M_}.
    // pre was read BEFORE step (M_-1)'s fold -> patch with meT1s*I.
#define STEPB(M_, FIRST_)                                               \
    {                                                                   \
        const float sum = (FIRST_) ? pre : fmaf(meT1s, I, pre);         \
        float pnx = pre;                                                \
        if ((M_) < 63) pnx = rdlane_i(acc_cur, (M_) + 1);               \
        const float a  = fmaf(dtb, S, c1);                              \
        const float bb = fmaf(ndtb, I, 1.0f);                           \
        S = fmaf(bb, S, sum);                                           \
        I = I * a;                                                      \
        const bool cap = (L == (M_));                                   \
        oS = cap ? S : oS;                                              \
        oI = cap ? I : oI;                                              \
        acc_cur = fmaf(rm_##M_, I, acc_cur);                            \
        acc_nxt = fmaf(rn_##M_, I, acc_nxt);                            \
        pre = pnx;                                                      \
    }
#define STEP_GE1(M_) if ((M_) >= 1) STEPB(M_, false)
#define STEP_GE2(M_) if ((M_) >= 2) STEPB(M_, false)

    for (int c = 0; c < 16; ++c) {
        if (wid == 0) {
            if (c == 0) {
                // fold initial I0 (tau=0 term); lane0's rm_0 is the 0 pad
                acc_cur = rm_0 * I;
                acc_nxt = rn_0 * I;
                pre = rdlane_i(acc_cur, 1);
                STEPB(1, true)
                REP64(STEP_GE2)
            } else {
                // chunk-head merge: ONE consecutive-per-lane ds_read_b128
                const float4 pa = *(const float4*)&P[c & 1][L][0];
                const float ps = (pa.x + pa.y) + (pa.z + pa.w);   // slot3 = 0
                acc_cur = fmaf(dt2, ps, acc_nxt);  // scale raw P sums
                acc_nxt = 0.0f;
                pre = rdlane_i(acc_cur, 0);
                STEPB(0, true)
                REP64(STEP_GE1)
            }

            // ---- chunk epilogue (wave 0) ----
            const int j = 64 * c + L;
            const _Float16 hI = (_Float16)oI;
#pragma unroll
            for (int r = 0; r < 8; ++r) sIhR[r * SIH + 8 + (j - r)] = hI;

            const float oR = TOT - oS - oI;
            const size_t so = ((size_t)j * B_N + b) * 3;
            out[so + 0] = oS;
            out[so + 1] = oI;
            out[so + 2] = oR;

            float sm1 = __shfl_up(oS, 1);
            float im1 = __shfl_up(oI, 1);
            if (L == 0) { sm1 = carryS; im1 = carryI; }
            if (j > 0) {
                const float d0 = (oS - sm1) * invdt;
                const float d1 = (oI - im1) * invdt;
                const float d2 = -d0 - d1;
                const size_t dofs = ((size_t)(j - 1) * B_N + b) * 3;
                diff[dofs + 0] = d0;
                diff[dofs + 1] = d1;
                diff[dofs + 2] = d2;
            }
            carryS = rdlane_i(oS, 63);
            carryI = rdlane_i(oI, 63);
        } else if (c < 15) {
            // history dot for chunk c+1 over tau < 64c; 3 dot waves,
            // wave w handles segments s ≡ w (mod 3)
            const int w    = wid - 1;
            const int G    = 8 * c;
            const int idx0 = (T_N - 64 * (c + 1)) - R8;
            float p0 = 0.0f, p1 = 0.0f;
            int s = w;
            for (; s + NDW < G; s += 2 * NDW) {
                const h8_t mv0 = *(const h8_t*)&sMeH[idx0 + 8 * s];
                const h8_t iv0 = *(const h8_t*)&sIhR[iofs + 8 * s];
                const h8_t mv1 = *(const h8_t*)&sMeH[idx0 + 8 * (s + NDW)];
                const h8_t iv1 = *(const h8_t*)&sIhR[iofs + 8 * (s + NDW)];
                DOT8(p0, mv0, iv0)
                DOT8(p1, mv1, iv1)
            }
            if (s < G) {
                const h8_t mv0 = *(const h8_t*)&sMeH[idx0 + 8 * s];
                const h8_t iv0 = *(const h8_t*)&sIhR[iofs + 8 * s];
                DOT8(p0, mv0, iv0)
            }
            float p = p0 + p1;
            if (w == 0) {
                // tail fixup: tau = 64c - d, d = 1..f (raw, scaled at merge)
#pragma unroll
                for (int d = 1; d <= 7; ++d) {
                    const float ih = (float)sIhR[8 + 64 * c - d];   // row 0
                    if (d <= f) p = fmaf(mf[d - 1], ih, p);
                }
            }
            P[(c + 1) & 1][L][w] = p;
        }
        __syncthreads();
    }
#undef STEPB
#undef STEP_GE1
#undef STEP_GE2
}

// ---------------------------------------------------------------------------
// Launcher: me_kernel (2x512) then scan_kernel (256 blocks x 256 threads).
// d_ws layout: [0,4096) fp32 me; [4096,6144) fp16 me.
// ---------------------------------------------------------------------------
extern "C" void kernel_launch(void* const* d_in, const int* in_sizes, int n_in,
                              void* d_out, int out_size, void* d_ws, size_t ws_size,
                              hipStream_t stream) {
    const float* t     = (const float*)d_in[0];
    const float* y     = (const float*)d_in[1];
    const float* w1    = (const float*)d_in[2];
    const float* b1    = (const float*)d_in[3];
    const float* w2    = (const float*)d_in[4];
    const float* b2    = (const float*)d_in[5];
    const float* w3    = (const float*)d_in[6];
    const float* b3    = (const float*)d_in[7];
    const float* w4    = (const float*)d_in[8];
    const float* b4    = (const float*)d_in[9];
    const float* beta  = (const float*)d_in[10];
    const float* gamma = (const float*)d_in[11];

    float*    me_f = (float*)d_ws;
    _Float16* me_h = (_Float16*)((char*)d_ws + 4096);

    me_kernel<<<2, 512, 0, stream>>>(t, w1, b1, w2, b2, w3, b3, w4, b4, me_f, me_h);
    scan_kernel<<<B_N, 256, 0, stream>>>(me_f, me_h, t, y, beta, gamma, (float*)d_out);
}